// Round 1
// baseline (301.833 us; speedup 1.0000x reference)
//
#include <hip/hip_runtime.h>
#include <hip/hip_bf16.h>
#include <stdint.h>

#define D_MODEL 1024
#define NHEADS  16
#define HDIM    64
#define BB      2
#define TT      2048
#define MROWS   (BB*TT)      // 4096
#define GK      1024         // reduction dim for all projections

typedef __bf16 bf16_8 __attribute__((ext_vector_type(8)));
typedef float  f32x4  __attribute__((ext_vector_type(4)));
typedef unsigned short u16;

__device__ __forceinline__ u16 f2bf(float f) {
    union { float f; uint32_t u; } c; c.f = f;
    uint32_t u = c.u;
    uint32_t r = (u + 0x7FFFu + ((u >> 16) & 1u)) >> 16;
    return (u16)r;
}

__device__ __forceinline__ void gload16(const void* g, void* l) {
    __builtin_amdgcn_global_load_lds(
        (const __attribute__((address_space(1))) unsigned int*)g,
        (__attribute__((address_space(3))) unsigned int*)l,
        16, 0, 0);
}

// ---------------------------------------------------------------- convert
__global__ __launch_bounds__(256) void cvtk(
    const float* __restrict__ x,  const float* __restrict__ wq,
    const float* __restrict__ wk, const float* __restrict__ wv,
    const float* __restrict__ wo,
    u16* __restrict__ xb,  u16* __restrict__ wqb, u16* __restrict__ wkb,
    u16* __restrict__ wvb, u16* __restrict__ wob)
{
    int z = blockIdx.y;
    const float* in; u16* out; int n4;
    switch (z) {
        case 0: in = x;  out = xb;  n4 = MROWS*D_MODEL/4; break;
        case 1: in = wq; out = wqb; n4 = D_MODEL*D_MODEL/4; break;
        case 2: in = wk; out = wkb; n4 = D_MODEL*D_MODEL/4; break;
        case 3: in = wv; out = wvb; n4 = D_MODEL*D_MODEL/4; break;
        default: in = wo; out = wob; n4 = D_MODEL*D_MODEL/4; break;
    }
    for (int i = blockIdx.x*256 + threadIdx.x; i < n4; i += 1024*256) {
        float4 v = ((const float4*)in)[i];
        u16 o0 = f2bf(v.x), o1 = f2bf(v.y), o2 = f2bf(v.z), o3 = f2bf(v.w);
        uint2 pk;
        pk.x = (uint32_t)o0 | ((uint32_t)o1 << 16);
        pk.y = (uint32_t)o2 | ((uint32_t)o3 << 16);
        ((uint2*)out)[i] = pk;
    }
}

// ---------------------------------------------------------------- GEMM body
// C(128x128) tile of A(4096x1024) * B(1024x1024)^T, both bf16 row-major.
// mode 0: scatter bf16 into (B,H,T,D)   [Q,K]
// mode 1: scatter bf16 into (B,H,D,T)   [V transposed]
// mode 2: f32 row-major (4096x1024)     [final out]
__device__ __forceinline__ void gemm_body(
    const u16* __restrict__ A, const u16* __restrict__ Bm,
    void* __restrict__ dst, int mode)
{
    __shared__ u16 As[128*64];
    __shared__ u16 Bs[128*64];
    const int tid  = threadIdx.x;
    const int lane = tid & 63, w = tid >> 6;
    const int wr = w >> 1, wc = w & 1;
    const int g = lane >> 4, lr = lane & 15;
    const int bn = blockIdx.x & 7, bm = blockIdx.x >> 3;
    const int m0 = bm * 128, n0 = bn * 128;

    f32x4 acc[4][4];
    #pragma unroll
    for (int i = 0; i < 4; ++i)
        #pragma unroll
        for (int j = 0; j < 4; ++j)
            acc[i][j] = f32x4{0.f, 0.f, 0.f, 0.f};

    for (int k0 = 0; k0 < GK; k0 += 64) {
        // stage 128x64 tiles of A and B via global_load_lds (swizzled source)
        #pragma unroll
        for (int r = 0; r < 4; ++r) {
            int o   = r*256 + tid;              // 16B slot id 0..1023
            int row = o >> 3;
            int lc  = (o & 7) ^ (row & 7);      // inverse swizzle on source
            const char* ga = (const char*)(A  + (size_t)(m0+row)*GK + k0 + lc*8);
            const char* gb = (const char*)(Bm + (size_t)(n0+row)*GK + k0 + lc*8);
            char* la = (char*)As + (size_t)(r*256 + w*64)*16;   // wave-uniform base
            char* lb = (char*)Bs + (size_t)(r*256 + w*64)*16;
            gload16(ga, la);
            gload16(gb, lb);
        }
        __syncthreads();
        #pragma unroll
        for (int ks = 0; ks < 2; ++ks) {
            bf16_8 af[4], bfr[4];
            #pragma unroll
            for (int mt = 0; mt < 4; ++mt) {
                int row = wr*64 + mt*16 + lr;
                int ch  = (ks*4 + g) ^ (row & 7);
                af[mt] = *(const bf16_8*)((const char*)As + row*128 + ch*16);
            }
            #pragma unroll
            for (int nt = 0; nt < 4; ++nt) {
                int row = wc*64 + nt*16 + lr;
                int ch  = (ks*4 + g) ^ (row & 7);
                bfr[nt] = *(const bf16_8*)((const char*)Bs + row*128 + ch*16);
            }
            #pragma unroll
            for (int mt = 0; mt < 4; ++mt)
                #pragma unroll
                for (int nt = 0; nt < 4; ++nt)
                    acc[mt][nt] = __builtin_amdgcn_mfma_f32_16x16x32_bf16(
                        af[mt], bfr[nt], acc[mt][nt], 0, 0, 0);
        }
        __syncthreads();
    }

    // epilogue: C/D layout col=lane&15, row=4*(lane>>4)+reg
    #pragma unroll
    for (int mt = 0; mt < 4; ++mt) {
        #pragma unroll
        for (int nt = 0; nt < 4; ++nt) {
            #pragma unroll
            for (int r = 0; r < 4; ++r) {
                int row = m0 + wr*64 + mt*16 + g*4 + r;    // 0..4095
                int col = n0 + wc*64 + nt*16 + lr;         // 0..1023
                float v = acc[mt][nt][r];
                if (mode == 2) {
                    ((float*)dst)[(size_t)row*D_MODEL + col] = v;
                } else {
                    int b = row >> 11, t = row & (TT-1);
                    int h = col >> 6,  d = col & 63;
                    size_t idx = (mode == 0)
                        ? (((size_t)(b*NHEADS + h)*TT + t)*HDIM + d)
                        : (((size_t)(b*NHEADS + h)*HDIM + d)*TT + t);
                    ((u16*)dst)[idx] = f2bf(v);
                }
            }
        }
    }
}

__global__ __launch_bounds__(256) void gemm_qkv(
    const u16* __restrict__ xb,
    const u16* __restrict__ wqb, const u16* __restrict__ wkb, const u16* __restrict__ wvb,
    u16* __restrict__ Qb, u16* __restrict__ Kb, u16* __restrict__ VTb)
{
    int z = blockIdx.y;
    const u16* Bm = (z == 0) ? wqb : (z == 1) ? wkb : wvb;
    u16* dst      = (z == 0) ? Qb  : (z == 1) ? Kb  : VTb;
    gemm_body(xb, Bm, dst, (z == 2) ? 1 : 0);
}

__global__ __launch_bounds__(256) void gemm_out(
    const u16* __restrict__ AOb, const u16* __restrict__ wob, float* __restrict__ out)
{
    gemm_body(AOb, wob, out, 2);
}

// ---------------------------------------------------------------- attention
// grid (T/64, B*H); 4 waves/block; wave owns 16 q rows; KVBLK=32
__global__ __launch_bounds__(256) void attn_fwd(
    const u16* __restrict__ Qb, const u16* __restrict__ Kb,
    const u16* __restrict__ VTb, const unsigned char* __restrict__ mask,
    u16* __restrict__ AO)
{
    __shared__ u16 Plds[4][16*72];        // per-wave P tile, stride 72 bf16 (16B-aligned rows)
    const int tid = threadIdx.x, lane = tid & 63, w = tid >> 6;
    const int g = lane >> 4, lr = lane & 15;
    const int bh = blockIdx.y, b = bh >> 4, h = bh & 15;
    const int q0 = blockIdx.x*64 + w*16;

    const u16* Qh = Qb  + (size_t)bh*TT*HDIM;
    const u16* Kh = Kb  + (size_t)bh*TT*HDIM;
    const u16* Vh = VTb + (size_t)bh*HDIM*TT;

    bf16_8 aq[2];
    #pragma unroll
    for (int dc = 0; dc < 2; ++dc)
        aq[dc] = *(const bf16_8*)(Qh + (size_t)(q0+lr)*HDIM + dc*32 + g*8);

    f32x4 o[4];
    #pragma unroll
    for (int i = 0; i < 4; ++i) o[i] = f32x4{0.f, 0.f, 0.f, 0.f};
    float mst[4], lst[4];
    #pragma unroll
    for (int r = 0; r < 4; ++r) { mst[r] = -1e30f; lst[r] = 0.f; }

    const int kvend = (((q0 + 15) >> 5) + 1) << 5;   // per-wave causal bound
    for (int kv0 = 0; kv0 < kvend; kv0 += 32) {
        // ---- QK^T
        f32x4 s[2];
        #pragma unroll
        for (int nt = 0; nt < 2; ++nt) {
            bf16_8 bk0 = *(const bf16_8*)(Kh + (size_t)(kv0+nt*16+lr)*HDIM + g*8);
            bf16_8 bk1 = *(const bf16_8*)(Kh + (size_t)(kv0+nt*16+lr)*HDIM + 32 + g*8);
            f32x4 z = f32x4{0.f, 0.f, 0.f, 0.f};
            z = __builtin_amdgcn_mfma_f32_16x16x32_bf16(aq[0], bk0, z, 0, 0, 0);
            z = __builtin_amdgcn_mfma_f32_16x16x32_bf16(aq[1], bk1, z, 0, 0, 0);
            s[nt] = z;
        }
        // ---- scale + causal + padding mask
        unsigned char pm0 = mask[b*TT + kv0 + lr];
        unsigned char pm1 = mask[b*TT + kv0 + 16 + lr];
        #pragma unroll
        for (int nt = 0; nt < 2; ++nt) {
            int kv = kv0 + nt*16 + lr;
            unsigned char pmv = nt ? pm1 : pm0;
            #pragma unroll
            for (int r = 0; r < 4; ++r) {
                int q = q0 + g*4 + r;
                float v = s[nt][r] * 0.125f;
                if (kv > q || pmv) v = -1e30f;
                s[nt][r] = v;
            }
        }
        // ---- online softmax stats
        float nm[4], fsc[4];
        #pragma unroll
        for (int r = 0; r < 4; ++r) {
            float mx = fmaxf(s[0][r], s[1][r]);
            mx = fmaxf(mx, __shfl_xor(mx, 1));
            mx = fmaxf(mx, __shfl_xor(mx, 2));
            mx = fmaxf(mx, __shfl_xor(mx, 4));
            mx = fmaxf(mx, __shfl_xor(mx, 8));
            float newm = fmaxf(mst[r], mx);
            fsc[r] = __expf(mst[r] - newm);
            nm[r] = newm; mst[r] = newm;
        }
        float psum[4] = {0.f, 0.f, 0.f, 0.f};
        #pragma unroll
        for (int nt = 0; nt < 2; ++nt)
            #pragma unroll
            for (int r = 0; r < 4; ++r) {
                float sv = s[nt][r];
                float p = (sv <= -1e29f) ? 0.f : __expf(sv - nm[r]);
                s[nt][r] = p;
                psum[r] += p;
            }
        #pragma unroll
        for (int r = 0; r < 4; ++r) {
            float ps = psum[r];
            ps += __shfl_xor(ps, 1); ps += __shfl_xor(ps, 2);
            ps += __shfl_xor(ps, 4); ps += __shfl_xor(ps, 8);
            lst[r] = lst[r]*fsc[r] + ps;
        }
        #pragma unroll
        for (int dt = 0; dt < 4; ++dt)
            #pragma unroll
            for (int r = 0; r < 4; ++r)
                o[dt][r] *= fsc[r];
        // ---- P -> LDS (C/D layout in, A-frag layout out)
        u16* pl = &Plds[w][0];
        #pragma unroll
        for (int nt = 0; nt < 2; ++nt)
            #pragma unroll
            for (int r = 0; r < 4; ++r)
                pl[(g*4 + r)*72 + nt*16 + lr] = f2bf(s[nt][r]);
        asm volatile("s_waitcnt lgkmcnt(0)" ::: "memory");
        __builtin_amdgcn_sched_barrier(0);
        bf16_8 ap = *(const bf16_8*)(pl + lr*72 + g*8);
        // ---- PV (V^T rows are d, NT natural)
        #pragma unroll
        for (int dt = 0; dt < 4; ++dt) {
            bf16_8 bv = *(const bf16_8*)(Vh + (size_t)(dt*16+lr)*TT + kv0 + g*8);
            o[dt] = __builtin_amdgcn_mfma_f32_16x16x32_bf16(ap, bv, o[dt], 0, 0, 0);
        }
    }
    // ---- epilogue: write (B,T,H*D) bf16
    #pragma unroll
    for (int r = 0; r < 4; ++r) {
        float inv = (lst[r] > 0.f) ? 1.f/lst[r] : 0.f;
        int t = q0 + g*4 + r;
        #pragma unroll
        for (int dt = 0; dt < 4; ++dt) {
            float v = o[dt][r] * inv;
            AO[((size_t)(b*TT + t))*D_MODEL + h*HDIM + dt*16 + lr] = f2bf(v);
        }
    }
}

// ---------------------------------------------------------------- launch
extern "C" void kernel_launch(void* const* d_in, const int* in_sizes, int n_in,
                              void* d_out, int out_size, void* d_ws, size_t ws_size,
                              hipStream_t stream)
{
    const float* x  = (const float*)d_in[0];
    const unsigned char* mask = (const unsigned char*)d_in[1];
    const float* Wq = (const float*)d_in[2];
    const float* Wk = (const float*)d_in[3];
    const float* Wv = (const float*)d_in[4];
    const float* Wo = (const float*)d_in[5];
    float* out = (float*)d_out;

    char* ws = (char*)d_ws;
    u16* xb  = (u16*)(ws + 0);          // 8 MB (reused as AO after QKV)
    u16* wqb = (u16*)(ws + 8388608);    // 2 MB
    u16* wkb = (u16*)(ws + 10485760);
    u16* wvb = (u16*)(ws + 12582912);
    u16* wob = (u16*)(ws + 14680064);
    u16* Qb  = (u16*)(ws + 16777216);   // 8 MB
    u16* Kb  = (u16*)(ws + 25165824);   // 8 MB
    u16* VTb = (u16*)(ws + 33554432);   // 8 MB
    u16* AOb = xb;                      // alias: xb dead after QKV projections

    cvtk<<<dim3(1024, 5), 256, 0, stream>>>(x, Wq, Wk, Wv, Wo, xb, wqb, wkb, wvb, wob);
    gemm_qkv<<<dim3(256, 3), 256, 0, stream>>>(xb, wqb, wkb, wvb, Qb, Kb, VTb);
    attn_fwd<<<dim3(TT/64, BB*NHEADS), 256, 0, stream>>>(Qb, Kb, VTb, mask, AOb);
    gemm_out<<<dim3(256), 256, 0, stream>>>(AOb, wob, out);
}

// Round 2
// 195.323 us; speedup vs baseline: 1.5453x; 1.5453x over previous
//
#include <hip/hip_runtime.h>
#include <hip/hip_bf16.h>
#include <stdint.h>

#define D_MODEL 1024
#define NHEADS  16
#define HDIM    64
#define BB      2
#define TT      2048
#define MROWS   (BB*TT)      // 4096
#define GK      1024         // reduction dim for all projections

typedef __bf16 bf16_8 __attribute__((ext_vector_type(8)));
typedef float  f32x4  __attribute__((ext_vector_type(4)));
typedef unsigned short u16;

__device__ __forceinline__ u16 f2bf(float f) {
    union { float f; uint32_t u; } c; c.f = f;
    uint32_t u = c.u;
    uint32_t r = (u + 0x7FFFu + ((u >> 16) & 1u)) >> 16;
    return (u16)r;
}
__device__ __forceinline__ uint32_t pk2bf(float a, float b) {
    return (uint32_t)f2bf(a) | ((uint32_t)f2bf(b) << 16);
}

__device__ __forceinline__ void gload16(const void* g, void* l) {
    __builtin_amdgcn_global_load_lds(
        (const __attribute__((address_space(1))) unsigned int*)g,
        (__attribute__((address_space(3))) unsigned int*)l,
        16, 0, 0);
}

// ---------------------------------------------------------------- convert
__global__ __launch_bounds__(256) void cvtk(
    const float* __restrict__ x,  const float* __restrict__ wq,
    const float* __restrict__ wk, const float* __restrict__ wv,
    const float* __restrict__ wo,
    u16* __restrict__ xb,  u16* __restrict__ wqb, u16* __restrict__ wkb,
    u16* __restrict__ wvb, u16* __restrict__ wob)
{
    int z = blockIdx.y;
    const float* in; u16* out; int n4;
    switch (z) {
        case 0: in = x;  out = xb;  n4 = MROWS*D_MODEL/4; break;
        case 1: in = wq; out = wqb; n4 = D_MODEL*D_MODEL/4; break;
        case 2: in = wk; out = wkb; n4 = D_MODEL*D_MODEL/4; break;
        case 3: in = wv; out = wvb; n4 = D_MODEL*D_MODEL/4; break;
        default: in = wo; out = wob; n4 = D_MODEL*D_MODEL/4; break;
    }
    for (int i = blockIdx.x*256 + threadIdx.x; i < n4; i += 1024*256) {
        float4 v = ((const float4*)in)[i];
        uint2 pk;
        pk.x = pk2bf(v.x, v.y);
        pk.y = pk2bf(v.z, v.w);
        ((uint2*)out)[i] = pk;
    }
}

// ---------------------------------------------------------------- GEMM body
// C(128x128) tile of A(4096x1024) * B(1024x1024)^T, both bf16 row-major.
// mode 0: scatter bf16 into (B,H,T,D)   [Q (scaled), K]
// mode 1: scatter bf16 into (B,H,D,T)   [V transposed]
// mode 2: f32 row-major (4096x1024)     [final out]
__device__ __forceinline__ void gemm_body(
    const u16* __restrict__ A, const u16* __restrict__ Bm,
    void* __restrict__ dst, int mode, float oscale)
{
    __shared__ u16 As[128*64];
    __shared__ u16 Bs[128*64];
    const int tid  = threadIdx.x;
    const int lane = tid & 63, w = tid >> 6;
    const int wr = w >> 1, wc = w & 1;
    const int g = lane >> 4, lr = lane & 15;
    const int bn = blockIdx.x & 7, bm = blockIdx.x >> 3;
    const int m0 = bm * 128, n0 = bn * 128;

    f32x4 acc[4][4];
    #pragma unroll
    for (int i = 0; i < 4; ++i)
        #pragma unroll
        for (int j = 0; j < 4; ++j)
            acc[i][j] = f32x4{0.f, 0.f, 0.f, 0.f};

    for (int k0 = 0; k0 < GK; k0 += 64) {
        #pragma unroll
        for (int r = 0; r < 4; ++r) {
            int o   = r*256 + tid;
            int row = o >> 3;
            int lc  = (o & 7) ^ (row & 7);
            const char* ga = (const char*)(A  + (size_t)(m0+row)*GK + k0 + lc*8);
            const char* gb = (const char*)(Bm + (size_t)(n0+row)*GK + k0 + lc*8);
            char* la = (char*)As + (size_t)(r*256 + w*64)*16;
            char* lb = (char*)Bs + (size_t)(r*256 + w*64)*16;
            gload16(ga, la);
            gload16(gb, lb);
        }
        __syncthreads();
        #pragma unroll
        for (int ks = 0; ks < 2; ++ks) {
            bf16_8 af[4], bfr[4];
            #pragma unroll
            for (int mt = 0; mt < 4; ++mt) {
                int row = wr*64 + mt*16 + lr;
                int ch  = (ks*4 + g) ^ (row & 7);
                af[mt] = *(const bf16_8*)((const char*)As + row*128 + ch*16);
            }
            #pragma unroll
            for (int nt = 0; nt < 4; ++nt) {
                int row = wc*64 + nt*16 + lr;
                int ch  = (ks*4 + g) ^ (row & 7);
                bfr[nt] = *(const bf16_8*)((const char*)Bs + row*128 + ch*16);
            }
            #pragma unroll
            for (int mt = 0; mt < 4; ++mt)
                #pragma unroll
                for (int nt = 0; nt < 4; ++nt)
                    acc[mt][nt] = __builtin_amdgcn_mfma_f32_16x16x32_bf16(
                        af[mt], bfr[nt], acc[mt][nt], 0, 0, 0);
        }
        __syncthreads();
    }

    #pragma unroll
    for (int mt = 0; mt < 4; ++mt) {
        #pragma unroll
        for (int nt = 0; nt < 4; ++nt) {
            #pragma unroll
            for (int r = 0; r < 4; ++r) {
                int row = m0 + wr*64 + mt*16 + g*4 + r;
                int col = n0 + wc*64 + nt*16 + lr;
                float v = acc[mt][nt][r];
                if (mode == 2) {
                    ((float*)dst)[(size_t)row*D_MODEL + col] = v;
                } else {
                    v *= oscale;
                    int b = row >> 11, t = row & (TT-1);
                    int h = col >> 6,  d = col & 63;
                    size_t idx = (mode == 0)
                        ? (((size_t)(b*NHEADS + h)*TT + t)*HDIM + d)
                        : (((size_t)(b*NHEADS + h)*HDIM + d)*TT + t);
                    ((u16*)dst)[idx] = f2bf(v);
                }
            }
        }
    }
}

__global__ __launch_bounds__(256) void gemm_qkv(
    const u16* __restrict__ xb,
    const u16* __restrict__ wqb, const u16* __restrict__ wkb, const u16* __restrict__ wvb,
    u16* __restrict__ Qb, u16* __restrict__ Kb, u16* __restrict__ VTb)
{
    int z = blockIdx.y;
    const u16* Bm = (z == 0) ? wqb : (z == 1) ? wkb : wvb;
    u16* dst      = (z == 0) ? Qb  : (z == 1) ? Kb  : VTb;
    float sc      = (z == 0) ? 0.125f : 1.0f;     // fold 1/sqrt(64) into Q
    gemm_body(xb, Bm, dst, (z == 2) ? 1 : 0, sc);
}

__global__ __launch_bounds__(256) void gemm_out(
    const u16* __restrict__ AOb, const u16* __restrict__ wob, float* __restrict__ out)
{
    gemm_body(AOb, wob, out, 2, 1.0f);
}

// ---------------------------------------------------------------- attention
// grid (T/64, B*H); 4 waves/block; wave owns 16 q rows (q=lane&15 swapped layout);
// KVBLK=64 staged in LDS (double-buffered, XOR-swizzled), shared by all 4 waves.
__global__ __launch_bounds__(256) void attn_fwd(
    const u16* __restrict__ Qb, const u16* __restrict__ Kb,
    const u16* __restrict__ VTb, const unsigned char* __restrict__ mask,
    u16* __restrict__ AO)
{
    __shared__ u16 Ks[2][64*64];      // [buf][row(kv) 64][d 64], 16B chunks XOR-swizzled
    __shared__ u16 Vs[2][64*64];      // [buf][row(d) 64][kv 64]
    __shared__ u16 Pl[4][16*72];      // per-wave P tile [q 16][kv 64], stride 72 u16

    const int tid = threadIdx.x, lane = tid & 63, w = tid >> 6;
    const int g = lane >> 4, lr = lane & 15;
    const int bh = blockIdx.y, b = bh >> 4, h = bh & 15;
    const int qt = gridDim.x - 1 - blockIdx.x;        // heavy tiles dispatched first
    const int q0b = qt * 64;
    const int q0 = q0b + w*16;

    const u16* Qh = Qb  + (size_t)bh*TT*HDIM;
    const u16* Kh = Kb  + (size_t)bh*TT*HDIM;
    const u16* Vh = VTb + (size_t)bh*HDIM*TT;
    const unsigned char* mk = mask + b*TT;

    // Q as B-fragments: lane holds q-row (q0+lr), k = d = dc*32 + g*8 + j
    bf16_8 qf[2];
    #pragma unroll
    for (int dc = 0; dc < 2; ++dc)
        qf[dc] = *(const bf16_8*)(Qh + (size_t)(q0+lr)*HDIM + dc*32 + g*8);

    f32x4 o[4];
    #pragma unroll
    for (int i = 0; i < 4; ++i) o[i] = f32x4{0.f, 0.f, 0.f, 0.f};
    float m_run = -1e30f, l_run = 0.f;

    const int nt = q0b/64 + 1;        // kv tiles needed (uniform across block)

    // ---- cooperative K/V tile staging (linear LDS dest, pre-swizzled source)
    auto STAGE = [&](int t, int buf) {
        int kv0 = t*64;
        #pragma unroll
        for (int r = 0; r < 2; ++r) {
            int o_  = r*256 + tid;        // 16B slot 0..511 (row*8+chunk)
            int row = o_ >> 3;
            int c   = (o_ & 7) ^ (row & 7);
            char* lk = (char*)&Ks[buf][0] + (size_t)(r*256 + w*64)*16;
            char* lv = (char*)&Vs[buf][0] + (size_t)(r*256 + w*64)*16;
            gload16(Kh + (size_t)(kv0+row)*HDIM + c*8, lk);   // K row = kv
            gload16(Vh + (size_t)row*TT + kv0 + c*8, lv);     // V^T row = d
        }
    };

    STAGE(0, 0);
    __syncthreads();

    for (int t = 0; t < nt; ++t) {
        const int cur = t & 1;
        if (t+1 < nt) STAGE(t+1, cur^1);
        const int kv0 = t*64;
        const u16* Kc = &Ks[cur][0];
        const u16* Vc = &Vs[cur][0];

        // ---- QK^T swapped: S^T[kv][q] = mfma(K_rows, Q_rows)
        f32x4 s[4];
        #pragma unroll
        for (int kvb = 0; kvb < 4; ++kvb) {
            int row = kvb*16 + lr;                       // local kv row
            bf16_8 k0 = *(const bf16_8*)(Kc + row*64 + ((g    ) ^ (lr&7))*8);
            bf16_8 k1 = *(const bf16_8*)(Kc + row*64 + ((4 + g) ^ (lr&7))*8);
            f32x4 z = f32x4{0.f, 0.f, 0.f, 0.f};
            z = __builtin_amdgcn_mfma_f32_16x16x32_bf16(k0, qf[0], z, 0, 0, 0);
            z = __builtin_amdgcn_mfma_f32_16x16x32_bf16(k1, qf[1], z, 0, 0, 0);
            s[kvb] = z;   // lane: q = q0+lr, kv = kv0 + kvb*16 + 4g + reg
        }

        // ---- mask (Q pre-scaled by 1/8 at projection)
        const int q = q0 + lr;
        #pragma unroll
        for (int kvb = 0; kvb < 4; ++kvb) {
            uchar4 pm = *(const uchar4*)(mk + kv0 + kvb*16 + 4*g);
            int kvbase = kv0 + kvb*16 + 4*g;
            unsigned char pmr[4] = {pm.x, pm.y, pm.z, pm.w};
            #pragma unroll
            for (int r = 0; r < 4; ++r) {
                if (kvbase + r > q || pmr[r]) s[kvb][r] = -1e30f;
            }
        }

        // ---- online softmax (q owned by lane&15, replicated over 4 g-groups)
        float t0 = fmaxf(fmaxf(s[0][0], s[0][1]), fmaxf(s[0][2], s[0][3]));
        float t1 = fmaxf(fmaxf(s[1][0], s[1][1]), fmaxf(s[1][2], s[1][3]));
        float t2 = fmaxf(fmaxf(s[2][0], s[2][1]), fmaxf(s[2][2], s[2][3]));
        float t3 = fmaxf(fmaxf(s[3][0], s[3][1]), fmaxf(s[3][2], s[3][3]));
        float mx = fmaxf(fmaxf(t0, t1), fmaxf(t2, t3));
        mx = fmaxf(mx, __shfl_xor(mx, 16));
        mx = fmaxf(mx, __shfl_xor(mx, 32));
        float newm = fmaxf(m_run, mx);
        float fsc  = __expf(m_run - newm);
        m_run = newm;

        #pragma unroll
        for (int kvb = 0; kvb < 4; ++kvb)
            #pragma unroll
            for (int r = 0; r < 4; ++r)
                s[kvb][r] = __expf(s[kvb][r] - newm);

        float p0 = (s[0][0] + s[0][1]) + (s[0][2] + s[0][3]);
        float p1 = (s[1][0] + s[1][1]) + (s[1][2] + s[1][3]);
        float p2 = (s[2][0] + s[2][1]) + (s[2][2] + s[2][3]);
        float p3 = (s[3][0] + s[3][1]) + (s[3][2] + s[3][3]);
        float ps = (p0 + p1) + (p2 + p3);
        ps += __shfl_xor(ps, 16);
        ps += __shfl_xor(ps, 32);
        l_run = l_run*fsc + ps;

        // ---- rescale O (O rows live at q = 4g+r)
        float fscr[4];
        #pragma unroll
        for (int r = 0; r < 4; ++r) fscr[r] = __shfl(fsc, 4*g + r);
        #pragma unroll
        for (int dt = 0; dt < 4; ++dt)
            #pragma unroll
            for (int r = 0; r < 4; ++r)
                o[dt][r] *= fscr[r];

        // ---- P -> LDS (pairs pack in-lane; read back as PV A-frags)
        char* Pw = (char*)&Pl[w][0];
        #pragma unroll
        for (int kvb = 0; kvb < 4; ++kvb) {
            *(uint32_t*)(Pw + lr*144 + kvb*32 + g*8 + 0) = pk2bf(s[kvb][0], s[kvb][1]);
            *(uint32_t*)(Pw + lr*144 + kvb*32 + g*8 + 4) = pk2bf(s[kvb][2], s[kvb][3]);
        }
        asm volatile("s_waitcnt lgkmcnt(0)" ::: "memory");
        __builtin_amdgcn_sched_barrier(0);

        // ---- PV: O[q][d] += P[q][kv] V[kv][d], A = P rows (q=lr), B = V^T rows (d=lr)
        #pragma unroll
        for (int hh = 0; hh < 2; ++hh) {
            bf16_8 pa = *(const bf16_8*)(Pw + lr*144 + hh*64 + g*16);
            #pragma unroll
            for (int dt = 0; dt < 4; ++dt) {
                int row = dt*16 + lr;                    // d row
                bf16_8 vb = *(const bf16_8*)(Vc + row*64 + ((hh*4 + g) ^ (lr&7))*8);
                o[dt] = __builtin_amdgcn_mfma_f32_16x16x32_bf16(pa, vb, o[dt], 0, 0, 0);
            }
        }
        __syncthreads();   // stage(t+1) landed (implicit vmcnt0) + reads of cur done
    }

    // ---- epilogue
    float linv[4];
    #pragma unroll
    for (int r = 0; r < 4; ++r) {
        float lv = __shfl(l_run, 4*g + r);
        linv[r] = (lv > 0.f) ? 1.f/lv : 0.f;
    }
    #pragma unroll
    for (int dt = 0; dt < 4; ++dt)
        #pragma unroll
        for (int r = 0; r < 4; ++r) {
            int tq = q0 + 4*g + r;
            AO[((size_t)(b*TT + tq))*D_MODEL + h*HDIM + dt*16 + lr] = f2bf(o[dt][r]*linv[r]);
        }
}

// ---------------------------------------------------------------- launch
extern "C" void kernel_launch(void* const* d_in, const int* in_sizes, int n_in,
                              void* d_out, int out_size, void* d_ws, size_t ws_size,
                              hipStream_t stream)
{
    const float* x  = (const float*)d_in[0];
    const unsigned char* mask = (const unsigned char*)d_in[1];
    const float* Wq = (const float*)d_in[2];
    const float* Wk = (const float*)d_in[3];
    const float* Wv = (const float*)d_in[4];
    const float* Wo = (const float*)d_in[5];
    float* out = (float*)d_out;

    char* ws = (char*)d_ws;
    u16* xb  = (u16*)(ws + 0);          // 8 MB (reused as AO after QKV)
    u16* wqb = (u16*)(ws + 8388608);
    u16* wkb = (u16*)(ws + 10485760);
    u16* wvb = (u16*)(ws + 12582912);
    u16* wob = (u16*)(ws + 14680064);
    u16* Qb  = (u16*)(ws + 16777216);
    u16* Kb  = (u16*)(ws + 25165824);
    u16* VTb = (u16*)(ws + 33554432);
    u16* AOb = xb;

    cvtk<<<dim3(1024, 5), 256, 0, stream>>>(x, Wq, Wk, Wv, Wo, xb, wqb, wkb, wvb, wob);
    gemm_qkv<<<dim3(256, 3), 256, 0, stream>>>(xb, wqb, wkb, wvb, Qb, Kb, VTb);
    attn_fwd<<<dim3(TT/64, BB*NHEADS), 256, 0, stream>>>(Qb, Kb, VTb, mask, AOb);
    gemm_out<<<dim3(256), 256, 0, stream>>>(AOb, wob, out);
}